// Round 3
// baseline (879.836 us; speedup 1.0000x reference)
//
#include <hip/hip_runtime.h>

#define VOCAB 400000
#define DIM   300
#define HID   32
#define NOUT  2
#define BATCH 16384
#define SEQ   50

// K0: P[v][k] = dot(Vw[k], emb[v]) for all vocab rows. Streams emb (480 MB)
// exactly once, coalesced-ish (lane = row, float4 over dims; L1 absorbs the
// 1200B-stride line sharing). Vw (38.4 KB) broadcast from LDS.
// One lane per vocab row, 64 rows/wave, 256 rows/block.
__global__ __launch_bounds__(256) void dan_pre(
    const float* __restrict__ emb,
    const float* __restrict__ Vw,
    float*       __restrict__ P)
{
    __shared__ float vwlds[HID * DIM];  // 9600 floats = 38.4 KB
    for (int i = threadIdx.x; i < HID * DIM; i += 256)
        vwlds[i] = Vw[i];
    __syncthreads();

    const int row = blockIdx.x * 256 + threadIdx.x;
    if (row >= VOCAB) return;

    const float4* erow = (const float4*)(emb + (size_t)row * DIM);
    const float4* wt   = (const float4*)vwlds;  // float4 idx: k*75 + d4

    float acc[HID];
    #pragma unroll
    for (int k = 0; k < HID; ++k) acc[k] = 0.f;

    for (int d4 = 0; d4 < DIM / 4; ++d4) {
        const float4 ev = erow[d4];
        #pragma unroll
        for (int k = 0; k < HID; ++k) {
            const float4 w = wt[k * (DIM / 4) + d4];  // wave-uniform broadcast
            acc[k] = fmaf(ev.x, w.x, acc[k]);
            acc[k] = fmaf(ev.y, w.y, acc[k]);
            acc[k] = fmaf(ev.z, w.z, acc[k]);
            acc[k] = fmaf(ev.w, w.w, acc[k]);
        }
    }

    float4* prow = (float4*)(P + (size_t)row * HID);
    #pragma unroll
    for (int j = 0; j < HID / 4; ++j)
        prow[j] = make_float4(acc[4*j], acc[4*j+1], acc[4*j+2], acc[4*j+3]);
}

// K1: one wave per batch row. Gather 50 rows of P (128 B each, L3/L2-resident),
// 2 tokens per iteration (lane = (token_half, k)), reduce, relu, 2-logit dot.
__global__ __launch_bounds__(256) void dan_gather(
    const int*   __restrict__ tokens,
    const float* __restrict__ P,
    const float* __restrict__ Vb,
    const float* __restrict__ Ww,
    const float* __restrict__ Wb,
    float*       __restrict__ logits)
{
    const int wave = threadIdx.x >> 6;
    const int lane = threadIdx.x & 63;
    const int row  = blockIdx.x * 4 + wave;
    if (row >= BATCH) return;

    // One coalesced token load per wave.
    int tl = 0;
    if (lane < SEQ) tl = tokens[row * SEQ + lane];

    const int k    = lane & 31;
    const int half = lane >> 5;   // 0: even tokens, 1: odd tokens

    float acc = 0.f;
    #pragma unroll
    for (int i = 0; i < SEQ / 2; ++i) {
        const int t = __shfl(tl, 2 * i + half, 64);
        acc += P[(size_t)t * HID + k];   // independent 128B-segment gathers
    }
    acc += __shfl_xor(acc, 32, 64);      // combine even/odd halves

    float h = acc * (1.0f / (float)SEQ) + Vb[k];
    h = h > 0.f ? h : 0.f;

    float p0 = h * Ww[k];
    float p1 = h * Ww[HID + k];
    #pragma unroll
    for (int m = 16; m >= 1; m >>= 1) {
        p0 += __shfl_xor(p0, m, 64);
        p1 += __shfl_xor(p1, m, 64);
    }
    if (lane == 0)
        ((float2*)logits)[row] = make_float2(p0 + Wb[0], p1 + Wb[1]);
}

// K2: single block computes per-column (axis=0) max and log-sum-exp.
__global__ __launch_bounds__(1024) void dan_reduce(
    const float* __restrict__ logits, float* __restrict__ c)
{
    __shared__ float r0[1024];
    __shared__ float r1[1024];
    const int tid = threadIdx.x;
    const float4* lp = (const float4*)logits;  // {l0,l1,l0,l1} for 2 rows

    float m0 = -INFINITY, m1 = -INFINITY;
    for (int i = tid; i < BATCH / 2; i += 1024) {
        float4 v = lp[i];
        m0 = fmaxf(m0, fmaxf(v.x, v.z));
        m1 = fmaxf(m1, fmaxf(v.y, v.w));
    }
    r0[tid] = m0; r1[tid] = m1;
    __syncthreads();
    for (int s = 512; s > 0; s >>= 1) {
        if (tid < s) {
            r0[tid] = fmaxf(r0[tid], r0[tid + s]);
            r1[tid] = fmaxf(r1[tid], r1[tid + s]);
        }
        __syncthreads();
    }
    m0 = r0[0]; m1 = r1[0];
    __syncthreads();

    float s0 = 0.f, s1 = 0.f;
    for (int i = tid; i < BATCH / 2; i += 1024) {
        float4 v = lp[i];
        s0 += __expf(v.x - m0) + __expf(v.z - m0);
        s1 += __expf(v.y - m1) + __expf(v.w - m1);
    }
    r0[tid] = s0; r1[tid] = s1;
    __syncthreads();
    for (int s = 512; s > 0; s >>= 1) {
        if (tid < s) {
            r0[tid] += r0[tid + s];
            r1[tid] += r1[tid + s];
        }
        __syncthreads();
    }
    if (tid == 0) {
        c[0] = m0 + __logf(r0[0]);
        c[1] = m1 + __logf(r1[0]);
    }
}

// K3: out[b][j] = logits[b][j] - c[j], float2-vectorized.
__global__ __launch_bounds__(256) void dan_final(
    const float* __restrict__ logits, const float* __restrict__ c,
    float* __restrict__ out)
{
    const int b = blockIdx.x * blockDim.x + threadIdx.x;
    if (b < BATCH) {
        float2 v = ((const float2*)logits)[b];
        ((float2*)out)[b] = make_float2(v.x - c[0], v.y - c[1]);
    }
}

extern "C" void kernel_launch(void* const* d_in, const int* in_sizes, int n_in,
                              void* d_out, int out_size, void* d_ws, size_t ws_size,
                              hipStream_t stream) {
    const int*   tokens = (const int*)  d_in[0];
    const float* emb    = (const float*)d_in[1];
    const float* Vw     = (const float*)d_in[2];
    const float* Vb     = (const float*)d_in[3];
    const float* Ww     = (const float*)d_in[4];
    const float* Wb     = (const float*)d_in[5];
    float* out = (float*)d_out;

    float* P      = (float*)d_ws;                   // VOCAB*HID floats = 51.2 MB
    float* logits = P + (size_t)VOCAB * HID;        // BATCH*2 floats = 128 KB
    float* c      = logits + BATCH * NOUT;          // 2 floats

    dan_pre   <<<(VOCAB + 255) / 256, 256, 0, stream>>>(emb, Vw, P);
    dan_gather<<<BATCH / 4, 256, 0, stream>>>(tokens, P, Vb, Ww, Wb, logits);
    dan_reduce<<<1, 1024, 0, stream>>>(logits, c);
    dan_final <<<(BATCH + 255) / 256, 256, 0, stream>>>(logits, c, out);
}